// Round 4
// baseline (97.161 us; speedup 1.0000x reference)
//
#include <hip/hip_runtime.h>
#include <stdint.h>

// SHA-256 round constants — used as compile-time literals via Kc[<const>]
constexpr uint32_t Kc[64] = {
    1116352408u, 1899447441u, 3049323471u, 3921009573u,  961987163u, 1508970993u,
    2453635748u, 2870763221u, 3624381080u,  310598401u,  607225278u, 1426881987u,
    1925078388u, 2162078206u, 2614888103u, 3248222580u, 3835390401u, 4022224774u,
     264347078u,  604807628u,  770255983u, 1249150122u, 1555081692u, 1996064986u,
    2554220882u, 2821834349u, 2952996808u, 3210313671u, 3336571891u, 3584528711u,
     113926993u,  338241895u,  666307205u,  773529912u, 1294757372u, 1396182291u,
    1695183700u, 1986661051u, 2177026350u, 2456956037u, 2730485921u, 2820302411u,
    3259730800u, 3345764771u, 3516065817u, 3600352804u, 4094571909u,  275423344u,
     430227734u,  506948616u,  659060556u,  883997877u,  958139571u, 1322822218u,
    1537002063u, 1747873779u, 1955562222u, 2024104815u, 2227730452u, 2361852424u,
    2428436474u, 2756734187u, 3204031479u, 3329325298u
};

#define ROTR(x,n) (((x) >> (n)) | ((x) << (32 - (n))))

// One round. Register names rotate by the caller, so no shift-moves needed.
// ch  = (e&f)|(~e&g)  -> v_bfi_b32(e, f, g)   (disjoint masks, | == ^)
// maj = (nx&c)|(~nx&b), nx=a^b -> 1 xor + v_bfi_b32 (2 ops, no carried state)
#define RND(a,b,c,d,e,f,g,h,K,w) {                                        \
    uint32_t t1 = h + (ROTR(e,6) ^ ROTR(e,11) ^ ROTR(e,25))               \
                    + ((e & f) | (~e & g)) + (K) + (w);                   \
    uint32_t nx = a ^ b;                                                  \
    uint32_t t2 = (ROTR(a,2) ^ ROTR(a,13) ^ ROTR(a,22))                   \
                    + ((nx & c) | (~nx & b));                             \
    d += t1; h = t1 + t2; }

#define R0(K,w) RND(a,b,c,d,e,f,g,h,K,w)
#define R1(K,w) RND(h,a,b,c,d,e,f,g,K,w)
#define R2(K,w) RND(g,h,a,b,c,d,e,f,K,w)
#define R3(K,w) RND(f,g,h,a,b,c,d,e,K,w)
#define R4(K,w) RND(e,f,g,h,a,b,c,d,K,w)
#define R5(K,w) RND(d,e,f,g,h,a,b,c,K,w)
#define R6(K,w) RND(c,d,e,f,g,h,a,b,K,w)
#define R7(K,w) RND(b,c,d,e,f,g,h,a,K,w)

// Schedule expansion: wA += s0(wB) + wC + s1(wD)
#define WEXP(wA,wB,wC,wD)                                                 \
    wA += (ROTR(wB,7) ^ ROTR(wB,18) ^ ((wB) >> 3)) + (wC)                 \
        + (ROTR(wD,17) ^ ROTR(wD,19) ^ ((wD) >> 10));

__device__ __forceinline__ uint32_t pack_be(uint4 v) {
    return (v.x << 24) | (v.y << 16) | (v.z << 8) | v.w;
}

// LDS layout: 256 messages x 16 packed words, padded to stride 17
// (gcd(17,32)=1 -> phase-2 reads at word-stride 17 hit all banks, 2-way = free;
//  phase-1 writes land mostly 2-3 way. 17408 B -> 4 blocks/CU still fit.)
#define LDS_STRIDE 17

__global__ __launch_bounds__(256) void sha256_kernel(
        const int* __restrict__ msg, uint32_t* __restrict__ out, int n) {
    __shared__ uint32_t buf[256 * LDS_STRIDE];

    const int t = threadIdx.x;
    const int blockBase = blockIdx.x * 256;          // first message of block

    // ---- Phase 1: coalesced global stream -> pack big-endian -> LDS ----
    // Each uint4 = 4 consecutive byte-ints = one message word. Wave reads
    // 4 KB contiguous per iteration (perfectly coalesced, every line used
    // exactly once).
    const uint4* g4 = reinterpret_cast<const uint4*>(msg);
    const size_t gbase = (size_t)blockBase * 16;     // uint4 units

    if (blockBase + 256 <= n) {
        // full block — no guards in the hot path
        #pragma unroll
        for (int j = 0; j < 16; ++j) {
            uint4 v = g4[gbase + (size_t)j * 256 + t];
            int mLocal = j * 16 + (t >> 4);
            int w = t & 15;
            buf[mLocal * LDS_STRIDE + w] = pack_be(v);
        }
    } else {
        #pragma unroll
        for (int j = 0; j < 16; ++j) {
            int mLocal = j * 16 + (t >> 4);
            int w = t & 15;
            uint32_t p = 0;
            if (blockBase + mLocal < n) {
                uint4 v = g4[gbase + (size_t)j * 256 + t];
                p = pack_be(v);
            }
            buf[mLocal * LDS_STRIDE + w] = p;
        }
    }
    __syncthreads();

    const uint32_t tid = blockBase + t;
    if (tid >= (uint32_t)n) return;

    // ---- Phase 2: read own message from LDS (stride-17, conflict-free) ----
    const uint32_t* mb = &buf[t * LDS_STRIDE];
    uint32_t w0  = mb[0],  w1  = mb[1],  w2  = mb[2],  w3  = mb[3];
    uint32_t w4  = mb[4],  w5  = mb[5],  w6  = mb[6],  w7  = mb[7];
    uint32_t w8  = mb[8],  w9  = mb[9],  w10 = mb[10], w11 = mb[11];
    uint32_t w12 = mb[12], w13 = mb[13], w14 = mb[14], w15 = mb[15];

    uint32_t a = 1779033703u, b = 3144134277u, c = 1013904242u, d = 2773480762u;
    uint32_t e = 1359893119u, f = 2600822924u, g =  528734635u, h = 1541459225u;

    // Rounds 0..15 (rounds 0-1 partially constant-fold: a..h are literals)
    R0(Kc[0],w0)  R1(Kc[1],w1)  R2(Kc[2],w2)  R3(Kc[3],w3)
    R4(Kc[4],w4)  R5(Kc[5],w5)  R6(Kc[6],w6)  R7(Kc[7],w7)
    R0(Kc[8],w8)  R1(Kc[9],w9)  R2(Kc[10],w10) R3(Kc[11],w11)
    R4(Kc[12],w12) R5(Kc[13],w13) R6(Kc[14],w14) R7(Kc[15],w15)

    // Rounds 16..63: expand-then-round, rolling 16-word window
    WEXP(w0,w1,w9,w14)    R0(Kc[16],w0)
    WEXP(w1,w2,w10,w15)   R1(Kc[17],w1)
    WEXP(w2,w3,w11,w0)    R2(Kc[18],w2)
    WEXP(w3,w4,w12,w1)    R3(Kc[19],w3)
    WEXP(w4,w5,w13,w2)    R4(Kc[20],w4)
    WEXP(w5,w6,w14,w3)    R5(Kc[21],w5)
    WEXP(w6,w7,w15,w4)    R6(Kc[22],w6)
    WEXP(w7,w8,w0,w5)     R7(Kc[23],w7)
    WEXP(w8,w9,w1,w6)     R0(Kc[24],w8)
    WEXP(w9,w10,w2,w7)    R1(Kc[25],w9)
    WEXP(w10,w11,w3,w8)   R2(Kc[26],w10)
    WEXP(w11,w12,w4,w9)   R3(Kc[27],w11)
    WEXP(w12,w13,w5,w10)  R4(Kc[28],w12)
    WEXP(w13,w14,w6,w11)  R5(Kc[29],w13)
    WEXP(w14,w15,w7,w12)  R6(Kc[30],w14)
    WEXP(w15,w0,w8,w13)   R7(Kc[31],w15)

    WEXP(w0,w1,w9,w14)    R0(Kc[32],w0)
    WEXP(w1,w2,w10,w15)   R1(Kc[33],w1)
    WEXP(w2,w3,w11,w0)    R2(Kc[34],w2)
    WEXP(w3,w4,w12,w1)    R3(Kc[35],w3)
    WEXP(w4,w5,w13,w2)    R4(Kc[36],w4)
    WEXP(w5,w6,w14,w3)    R5(Kc[37],w5)
    WEXP(w6,w7,w15,w4)    R6(Kc[38],w6)
    WEXP(w7,w8,w0,w5)     R7(Kc[39],w7)
    WEXP(w8,w9,w1,w6)     R0(Kc[40],w8)
    WEXP(w9,w10,w2,w7)    R1(Kc[41],w9)
    WEXP(w10,w11,w3,w8)   R2(Kc[42],w10)
    WEXP(w11,w12,w4,w9)   R3(Kc[43],w11)
    WEXP(w12,w13,w5,w10)  R4(Kc[44],w12)
    WEXP(w13,w14,w6,w11)  R5(Kc[45],w13)
    WEXP(w14,w15,w7,w12)  R6(Kc[46],w14)
    WEXP(w15,w0,w8,w13)   R7(Kc[47],w15)

    WEXP(w0,w1,w9,w14)    R0(Kc[48],w0)
    WEXP(w1,w2,w10,w15)   R1(Kc[49],w1)
    WEXP(w2,w3,w11,w0)    R2(Kc[50],w2)
    WEXP(w3,w4,w12,w1)    R3(Kc[51],w3)
    WEXP(w4,w5,w13,w2)    R4(Kc[52],w4)
    WEXP(w5,w6,w14,w3)    R5(Kc[53],w5)
    WEXP(w6,w7,w15,w4)    R6(Kc[54],w6)
    WEXP(w7,w8,w0,w5)     R7(Kc[55],w7)
    WEXP(w8,w9,w1,w6)     R0(Kc[56],w8)
    WEXP(w9,w10,w2,w7)    R1(Kc[57],w9)
    WEXP(w10,w11,w3,w8)   R2(Kc[58],w10)
    WEXP(w11,w12,w4,w9)   R3(Kc[59],w11)
    WEXP(w12,w13,w5,w10)  R4(Kc[60],w12)
    WEXP(w13,w14,w6,w11)  R5(Kc[61],w13)
    WEXP(w14,w15,w7,w12)  R6(Kc[62],w14)
    WEXP(w15,w0,w8,w13)   R7(Kc[63],w15)

    // Output: (B, 8) raw uint32 words, 32 contiguous bytes per thread.
    uint4* o = reinterpret_cast<uint4*>(out) + (size_t)tid * 2;
    o[0] = make_uint4(1779033703u + a, 3144134277u + b,
                      1013904242u + c, 2773480762u + d);
    o[1] = make_uint4(1359893119u + e, 2600822924u + f,
                       528734635u + g, 1541459225u + h);
}

extern "C" void kernel_launch(void* const* d_in, const int* in_sizes, int n_in,
                              void* d_out, int out_size, void* d_ws, size_t ws_size,
                              hipStream_t stream) {
    const int* msg = (const int*)d_in[0];
    uint32_t* out = (uint32_t*)d_out;
    const int n = in_sizes[0] / 64;   // B messages
    const int block = 256;
    const int grid = (n + block - 1) / block;
    sha256_kernel<<<grid, block, 0, stream>>>(msg, out, n);
}